// Round 1
// 699.093 us; speedup vs baseline: 1.0540x; 1.0540x over previous
//
#include <hip/hip_runtime.h>

#define TOKENS 4096
#define IN_F   8192
#define OUT_F  8192
#define BK     64
#define TILEB  24576          /* per-buffer LDS bytes: A 128*64 + B 256*64 */
#define NT     (IN_F / BK)    /* 128 K-tiles */

typedef int v4i __attribute__((ext_vector_type(4)));

__device__ __forceinline__ void gload_lds16(const void* g, void* l) {
    __builtin_amdgcn_global_load_lds(
        (const __attribute__((address_space(1))) void*)g,
        (__attribute__((address_space(3))) void*)l, 16, 0, 0);
}

// ---------------- Kernel 1: per-row absmax + int8 quantize ----------------
__global__ __launch_bounds__(256) void quant_kernel(const float* __restrict__ x,
                                                    signed char* __restrict__ xq,
                                                    float* __restrict__ recip_s) {
    const int row = blockIdx.x;
    const int t   = threadIdx.x;
    const float4* xr = (const float4*)(x + (size_t)row * IN_F);
    float4 v[8];
    float m = 0.f;
#pragma unroll
    for (int i = 0; i < 8; ++i) {
        v[i] = xr[t + 256 * i];
        m = fmaxf(m, fmaxf(fmaxf(fabsf(v[i].x), fabsf(v[i].y)),
                           fmaxf(fabsf(v[i].z), fabsf(v[i].w))));
    }
#pragma unroll
    for (int off = 32; off > 0; off >>= 1)
        m = fmaxf(m, __shfl_xor(m, off));
    __shared__ float wmax[4];
    if ((t & 63) == 0) wmax[t >> 6] = m;
    __syncthreads();
    m = fmaxf(fmaxf(wmax[0], wmax[1]), fmaxf(wmax[2], wmax[3]));
    m = fmaxf(m, 1e-5f);
    const float s = 127.0f / m;          // matches ref: s = 127/clip(max,1e-5)
    if (t == 0) recip_s[row] = m / 127.0f;
    unsigned int* out = (unsigned int*)(xq + (size_t)row * IN_F);
#pragma unroll
    for (int i = 0; i < 8; ++i) {
        int a = (int)fminf(fmaxf(rintf(v[i].x * s), -128.f), 127.f);
        int b = (int)fminf(fmaxf(rintf(v[i].y * s), -128.f), 127.f);
        int c = (int)fminf(fmaxf(rintf(v[i].z * s), -128.f), 127.f);
        int d = (int)fminf(fmaxf(rintf(v[i].w * s), -128.f), 127.f);
        out[t + 256 * i] = (a & 255) | ((b & 255) << 8) | ((c & 255) << 16) | ((d & 255) << 24);
    }
}

// ---------------- Kernel 2: weight int32 {0,1} -> int8 ----------------
__global__ __launch_bounds__(256) void pack_w(const int* __restrict__ w,
                                              unsigned int* __restrict__ w8) {
    const size_t idx = (size_t)blockIdx.x * 256 + threadIdx.x;
    int4 a = ((const int4*)w)[idx];
    w8[idx] = (a.x & 255) | ((a.y & 255) << 8) | ((a.z & 255) << 16) | ((a.w & 255) << 24);
}

// ---------------- Kernel 3: i8 GEMM, 128x256 tile, BK=64, swizzled LDS ----
// Depth-2 software pipeline (T3+T4): triple-buffered LDS, counted
// s_waitcnt vmcnt(6) per K-step (never a full drain in the main loop),
// one raw s_barrier per K-step. LDS chunk swizzle unchanged:
// 16B chunk c of row r stored at position c ^ ((r>>1)&3), applied at the
// global source address (gload_lds dest must stay linear) and at reads.
__global__ __launch_bounds__(256, 2) void gemm_kernel(const signed char* __restrict__ A,
                                                      const signed char* __restrict__ B,
                                                      const float* __restrict__ recip_s,
                                                      const float* __restrict__ wscale,
                                                      const float* __restrict__ bias,
                                                      float* __restrict__ out) {
    __shared__ signed char smem[3 * TILEB];   // 72 KB -> 2 blocks/CU
    const int t    = threadIdx.x;
    const int wave = t >> 6;
    const int lane = t & 63;
    const int m0 = blockIdx.y * 128;
    const int n0 = blockIdx.x * 256;
    const int wm = (wave >> 1) * 64;    // wave row offset (M)
    const int wn = (wave & 1) * 128;    // wave col offset (N)

    v4i acc[4][8] = {};

    // staging geometry: 256 threads x 16B = 4KB per gload (64 rows of 64B)
    const int rowS = t >> 2;                           // 0..63
    const int colS = ((t & 3) ^ ((t >> 3) & 3)) * 16;  // swizzled source chunk
    const signed char* gA = A + (size_t)(m0 + rowS) * IN_F + colS;
    const signed char* gB = B + (size_t)(n0 + rowS) * IN_F + colS;

    const int r16 = lane & 15;
    const int q   = lane >> 4;
    const int cOff = ((q ^ ((r16 >> 1) & 3)) * 16);    // swizzled read chunk

    // One STAGE = 6 x global_load_lds (16B each) = 24 KB tile, counts 6 on vmcnt.
#define STAGE(kt, buf) do {                                                  \
        signed char* lA = smem + (buf) * TILEB + t * 16;                     \
        signed char* lB = lA + 8192;                                         \
        const size_t k0 = (size_t)(kt) * BK;                                 \
        gload_lds16(gA + k0, lA);                                            \
        gload_lds16(gA + (size_t)64  * IN_F + k0, lA + 4096);                \
        gload_lds16(gB + k0, lB);                                            \
        gload_lds16(gB + (size_t)64  * IN_F + k0, lB + 4096);                \
        gload_lds16(gB + (size_t)128 * IN_F + k0, lB + 8192);                \
        gload_lds16(gB + (size_t)192 * IN_F + k0, lB + 12288);               \
    } while (0)

#define COMPUTE(buf) do {                                                    \
        const signed char* As_ = smem + (buf) * TILEB;                       \
        const signed char* Bs_ = As_ + 8192;                                 \
        v4i a[4], b[8];                                                      \
        _Pragma("unroll")                                                    \
        for (int i = 0; i < 4; ++i)                                          \
            a[i] = *(const v4i*)(As_ + (wm + i * 16 + r16) * 64 + cOff);     \
        _Pragma("unroll")                                                    \
        for (int j = 0; j < 8; ++j)                                          \
            b[j] = *(const v4i*)(Bs_ + (wn + j * 16 + r16) * 64 + cOff);     \
        __builtin_amdgcn_s_setprio(1);                                       \
        _Pragma("unroll")                                                    \
        for (int i = 0; i < 4; ++i)                                          \
            _Pragma("unroll")                                                \
            for (int j = 0; j < 8; ++j)                                      \
                acc[i][j] = __builtin_amdgcn_mfma_i32_16x16x64_i8(           \
                    a[i], b[j], acc[i][j], 0, 0, 0);                         \
        __builtin_amdgcn_s_setprio(0);                                       \
    } while (0)

    // Counted wait + raw barrier. Memory-clobber asm fences both sides so the
    // compiler cannot move LDS reads/stage ops across the barrier (s_barrier
    // intrinsic is IntrNoMem -- it does NOT order memory by itself).
#define WAITBAR(N) do {                                                      \
        asm volatile("s_waitcnt vmcnt(" #N ")" ::: "memory");                \
        __builtin_amdgcn_s_barrier();                                        \
        asm volatile("" ::: "memory");                                       \
    } while (0)

    // Prologue: tile0 staged+drained (once-per-kernel cost), tile1 in flight.
    STAGE(0, 0);
    asm volatile("s_waitcnt vmcnt(0)" ::: "memory");
    STAGE(1, 1);
    __builtin_amdgcn_s_barrier();
    asm volatile("" ::: "memory");

    // Main loop: 126 K-steps, unrolled x3 so buffer ids are compile-time.
    // Invariant at top of each body: outstanding vmem = tile (kt+1)'s 6 loads.
    for (int kt = 0; kt < NT - 2; kt += 3) {
        STAGE(kt + 2, 2); COMPUTE(0); WAITBAR(6);
        STAGE(kt + 3, 0); COMPUTE(1); WAITBAR(6);
        STAGE(kt + 4, 1); COMPUTE(2); WAITBAR(6);
    }
    // Tiles 126 (buf 0) and 127 (buf 1); only here does vmcnt drain to 0.
    COMPUTE(0);
    WAITBAR(0);
    COMPUTE(1);

#undef STAGE
#undef COMPUTE
#undef WAITBAR

    // Epilogue: dequant + bias (unchanged).
    const float rws = 1.0f / wscale[0];
#pragma unroll
    for (int i = 0; i < 4; ++i) {
#pragma unroll
        for (int r = 0; r < 4; ++r) {
            const int row = m0 + wm + i * 16 + q * 4 + r;
            const float rs = recip_s[row] * rws;
#pragma unroll
            for (int j = 0; j < 8; ++j) {
                const int col = n0 + wn + j * 16 + r16;
                out[(size_t)row * OUT_F + col] = (float)acc[i][j][r] * rs + bias[col];
            }
        }
    }
}

extern "C" void kernel_launch(void* const* d_in, const int* in_sizes, int n_in,
                              void* d_out, int out_size, void* d_ws, size_t ws_size,
                              hipStream_t stream) {
    const float* x      = (const float*)d_in[0];
    const int*   w      = (const int*)d_in[1];
    const float* wscale = (const float*)d_in[2];
    const float* bias   = (const float*)d_in[3];
    float* out = (float*)d_out;

    signed char* xq = (signed char*)d_ws;                          // 32 MB
    signed char* w8 = xq + (size_t)TOKENS * IN_F;                  // 64 MB
    float* recip_s  = (float*)(w8 + (size_t)OUT_F * IN_F);         // 16 KB

    quant_kernel<<<TOKENS, 256, 0, stream>>>(x, xq, recip_s);
    pack_w<<<(int)(((size_t)OUT_F * IN_F) / 4 / 256), 256, 0, stream>>>(w, (unsigned int*)w8);
    dim3 grid(OUT_F / 256, TOKENS / 128);
    gemm_kernel<<<grid, 256, 0, stream>>>(xq, w8, recip_s, wscale, bias, out);
}